// Round 1
// baseline (369.200 us; speedup 1.0000x reference)
//
#include <hip/hip_runtime.h>
#include <cstdint>

#define BLOCK_SIZE 256
#define NPOS 63   // 9*7 spatial positions per batch

// One thread per (batch, position). Recomputes z[n][f] and c[p] per thread
// (~5% redundant FLOPs) to stay LDS/sync-free; the 64x64 middle layer is the
// dominant cost and runs on wave-uniform scalar-loaded weights (s_load) with
// v_fma_f32 v,s,v — pure VALU, no VMEM in the hot loop.
__global__ __launch_bounds__(BLOCK_SIZE) void carnet_fused(
    const float* __restrict__ x,      // (B, 9, 7) flat
    const int*   __restrict__ adj,    // (B, 45)
    const float* __restrict__ ctx,    // (B, 45)
    const float* __restrict__ gcn_W,  // (7, 7)
    const float* __restrict__ gcn_b,  // (7)
    const float* __restrict__ ctx_W,  // (45, 63)
    const float* __restrict__ ctx_b,  // (63)
    const float* __restrict__ W1,     // (64, 2)
    const float* __restrict__ b1,     // (64)
    const float* __restrict__ W2,     // (64, 64)
    const float* __restrict__ b2,     // (64)
    const float* __restrict__ W3,     // (2, 64)
    const float* __restrict__ b3,     // (2)
    float* __restrict__ out,          // (B, 2, 9, 7) flat
    int total)
{
    const int tid = blockIdx.x * BLOCK_SIZE + threadIdx.x;
    if (tid >= total) return;
    const int b = tid / NPOS;
    const int p = tid - b * NPOS;
    const int n = p / 7;
    const int f = p - n * 7;

    // ---------------- adjacency -> 45-bit mask ----------------
    const int* ab = adj + b * 45;
    uint64_t am = 0;
#pragma unroll
    for (int i = 0; i < 45; ++i)
        am |= (uint64_t)(ab[i] != 0) << i;

    // Row i of upper triangle starts at S(i) = 9i - i(i-1)/2 (diag first).
    // A has diag forced to 1; row sum = 1 + popcount(j>i bits).
    float d[9];
#pragma unroll
    for (int i = 0; i < 9; ++i) {
        const int s = 9 * i - (i * (i - 1)) / 2;
        const int w = 8 - i;
        const uint64_t bits = (am >> (s + 1)) & ((1ull << w) - 1ull);
        const int rs = 1 + __popcll(bits);
        d[i] = __frsqrt_rn((float)rs);
    }

    // ---------------- z[n][f] = d[n] * sum_m wm * y[m][f] + gcn_b[f] ----
    // A is upper-triangular (only m>=n contribute for row n); wm = d[m] if
    // (m==n) or (m>n and adj bit set), else 0. Uniform control flow.
    const float* xb = x + b * 63;
    const int sn = 9 * n - (n * (n - 1)) / 2;
    float zacc = 0.f;
#pragma unroll
    for (int m = 0; m < 9; ++m) {
        int sh = sn + m - n;
        sh = sh < 0 ? 0 : sh;                     // clamp to avoid UB shift
        const bool conn = (m == n) || ((m > n) && ((am >> sh) & 1ull));
        const float wm = conn ? d[m] : 0.f;
        float ym = 0.f;                           // y[m][f] = x[m,:] . gcn_W[:,f]
#pragma unroll
        for (int k = 0; k < 7; ++k)
            ym = fmaf(xb[m * 7 + k], gcn_W[k * 7 + f], ym);
        zacc = fmaf(wm, ym, zacc);
    }
    const float zv = fmaf(d[n], zacc, gcn_b[f]);

    // ---------------- c[p] = relu(ctx . ctx_W[:,p] + ctx_b[p]) ----------
    const float* cb = ctx + b * 45;
    float cacc = ctx_b[p];
#pragma unroll
    for (int q = 0; q < 45; ++q)
        cacc = fmaf(cb[q], ctx_W[q * 63 + p], cacc);
    const float cv = fmaxf(cacc, 0.f);

    // ---------------- layer 1: 2 -> 64, relu ----------------------------
    float h1[64];
#pragma unroll
    for (int o = 0; o < 64; ++o)
        h1[o] = fmaxf(fmaf(W1[2 * o], zv, fmaf(W1[2 * o + 1], cv, b1[o])), 0.f);

    // ---------------- layer 2 (64x64) fused with layer 3 (64->2) --------
    float o0 = b3[0];
    float o1 = b3[1];
#pragma unroll 2
    for (int o = 0; o < 64; ++o) {
        float acc = b2[o];
#pragma unroll
        for (int k = 0; k < 64; ++k)
            acc = fmaf(W2[o * 64 + k], h1[k], acc);
        acc = fmaxf(acc, 0.f);                    // h2[o], never stored
        o0 = fmaf(W3[o], acc, o0);
        o1 = fmaf(W3[64 + o], acc, o1);
    }

    float* ob = out + b * 126 + p;
    ob[0]  = o0;   // channel 0
    ob[63] = o1;   // channel 1
}

extern "C" void kernel_launch(void* const* d_in, const int* in_sizes, int n_in,
                              void* d_out, int out_size, void* d_ws, size_t ws_size,
                              hipStream_t stream) {
    const float* x     = (const float*)d_in[0];
    const int*   adj   = (const int*)  d_in[1];
    const float* ctx   = (const float*)d_in[2];
    const float* gcn_W = (const float*)d_in[3];
    const float* gcn_b = (const float*)d_in[4];
    const float* ctx_W = (const float*)d_in[5];
    const float* ctx_b = (const float*)d_in[6];
    const float* W1    = (const float*)d_in[7];
    const float* b1    = (const float*)d_in[8];
    const float* W2    = (const float*)d_in[9];
    const float* b2    = (const float*)d_in[10];
    const float* W3    = (const float*)d_in[11];
    const float* b3    = (const float*)d_in[12];
    float* out = (float*)d_out;

    const int total = in_sizes[0];  // B * 63 positions
    const int grid = (total + BLOCK_SIZE - 1) / BLOCK_SIZE;
    carnet_fused<<<grid, BLOCK_SIZE, 0, stream>>>(
        x, adj, ctx, gcn_W, gcn_b, ctx_W, ctx_b,
        W1, b1, W2, b2, W3, b3, out, total);
}